// Round 7
// baseline (216.376 us; speedup 1.0000x reference)
//
#include <hip/hip_runtime.h>
#include <hip/hip_fp16.h>
#include <hip/hip_bf16.h>

#define N_TOT 65536
#define D_DIM 512
#define K_DIM 64
#define NC    32                // n-rows per chunk (one MFMA K=32 step)
#define GSZ   (K_DIM * D_DIM)   // 32768 elements of partial G
#define NBLK  512               // k1 blocks: 2 per CU

typedef __bf16   bf16x8 __attribute__((ext_vector_type(8)));
typedef float    f32x4  __attribute__((ext_vector_type(4)));
typedef _Float16 half8  __attribute__((ext_vector_type(8)));

union pk4 { unsigned int u[4]; bf16x8 v; };

__device__ __forceinline__ unsigned int pack2(float a, float b) {
    __hip_bfloat162 t = __float22bfloat162_rn(make_float2(a, b));
    union { __hip_bfloat162 h; unsigned int u; } r; r.h = t;
    return r.u;
}

typedef __attribute__((address_space(3))) void       lds_void;
typedef __attribute__((address_space(1))) const void gbl_void;

__device__ __forceinline__ void dma16(const float* g, float* l) {
    __builtin_amdgcn_global_load_lds((gbl_void*)g, (lds_void*)l, 16, 0, 0);
}

// K1 v7: 512 blocks x 512 thr, 72 KB LDS -> 2 co-resident blocks/CU.
// R3-R6 all stuck at ~70 us (2.3 TB/s): every variant had 1 block/CU, so the
// vmcnt(0) drain at each __syncthreads idled the CU's memory pipe with no
// other resident block to cover it (37% duty). Two blocks anti-phase their
// drain/issue windows (m114 cross-wave overlap) -> duty ~1.
extern "C" __global__ void __launch_bounds__(512, 4)
k1_partial(const float* __restrict__ h, const float* __restrict__ F,
           float* __restrict__ trw_out, unsigned short* __restrict__ gpart,
           float* __restrict__ out, int rowsPerBlock) {
    __shared__ float hbuf[NC][D_DIM];   // 64 KB fp32 [n][d]
    __shared__ float fbuf[NC][K_DIM];   //  8 KB fp32 [n][k]
    __shared__ float red[8];

    const int tid = threadIdx.x;
    const int b   = blockIdx.x;
    if (b == 0 && tid == 0) out[0] = 0.0f;        // d_out poisoned; zero before K2

    const int wave = tid >> 6;    // 0..7 ; wave owns d in [64w, 64w+64)
    const int lane = tid & 63;
    const int m    = lane & 15;
    const int q    = lane >> 4;

    const int row0    = b * rowsPerBlock;
    const int nChunks = rowsPerBlock / NC;

    f32x4 acc[4][4];              // [kt][dt]
    #pragma unroll
    for (int kt = 0; kt < 4; ++kt)
        #pragma unroll
        for (int dt = 0; dt < 4; ++dt)
            acc[kt][dt] = (f32x4){0.f, 0.f, 0.f, 0.f};

    float trw = 0.f;

    for (int c = 0; c < nChunks; ++c) {
        const int r0 = row0 + c * NC;
        // ---- stage: wave w DMAs h rows 4w..4w+3 (2 KB each) + F rows 4w..4w+3
        {
            const float* g = h + (size_t)(r0 + 4 * wave) * D_DIM + lane * 4;
            #pragma unroll
            for (int rr = 0; rr < 4; ++rr)
                #pragma unroll
                for (int hf = 0; hf < 2; ++hf)
                    dma16(g + rr * D_DIM + hf * 256, &hbuf[4 * wave + rr][hf * 256]);
            const float* gf = F + (size_t)(r0 + 4 * wave) * K_DIM + lane * 4;
            dma16(gf, &fbuf[4 * wave][0]);       // 1 KB = 4 F rows
        }
        __syncthreads();                          // DMA landed (vmcnt(0) drain)

        // ---- fragments + MFMA ----
        bf16x8 bfrag[4], afrag[4];
        #pragma unroll
        for (int dt = 0; dt < 4; ++dt) {
            float v[8];
            #pragma unroll
            for (int j = 0; j < 8; ++j) {
                v[j] = hbuf[q * 8 + j][wave * 64 + dt * 16 + m];
                trw += v[j] * v[j];               // each (n,d) once per block
            }
            pk4 pp;
            #pragma unroll
            for (int jj = 0; jj < 4; ++jj) pp.u[jj] = pack2(v[2*jj], v[2*jj+1]);
            bfrag[dt] = pp.v;
        }
        #pragma unroll
        for (int kt = 0; kt < 4; ++kt) {
            float v[8];
            #pragma unroll
            for (int j = 0; j < 8; ++j)
                v[j] = fbuf[q * 8 + j][kt * 16 + m];
            pk4 pp;
            #pragma unroll
            for (int jj = 0; jj < 4; ++jj) pp.u[jj] = pack2(v[2*jj], v[2*jj+1]);
            afrag[kt] = pp.v;
        }
        #pragma unroll
        for (int kt = 0; kt < 4; ++kt)
            #pragma unroll
            for (int dt = 0; dt < 4; ++dt)
                acc[kt][dt] = __builtin_amdgcn_mfma_f32_16x16x32_bf16(
                    afrag[kt], bfrag[dt], acc[kt][dt], 0, 0, 0);

        __syncthreads();                          // consumed; next DMA may overwrite
    }

    // ---- epilogue: partial G -> fp16 ----
    unsigned short* gp = gpart + (size_t)b * GSZ;
    #pragma unroll
    for (int kt = 0; kt < 4; ++kt)
        #pragma unroll
        for (int dt = 0; dt < 4; ++dt)
            #pragma unroll
            for (int r = 0; r < 4; ++r) {
                const int k = kt * 16 + q * 4 + r;      // C/D row
                const int d = wave * 64 + dt * 16 + m;  // C/D col
                __half hv = __float2half(acc[kt][dt][r]);
                gp[k * D_DIM + d] = *(unsigned short*)&hv;
            }

    // ---- tr_wtw partial ----
    #pragma unroll
    for (int off = 32; off > 0; off >>= 1) trw += __shfl_down(trw, off, 64);
    if (lane == 0) red[wave] = trw;
    __syncthreads();
    if (tid == 0) {
        float s = 0.f;
        #pragma unroll
        for (int w = 0; w < 8; ++w) s += red[w];
        trw_out[b] = s;
    }
}

// K2: out = sum_b trw[b] - sum_{k,d} (sum_b Gpart[b][k,d])^2   (256 blocks)
extern "C" __global__ void __launch_bounds__(512)
k2_reduce(const float* __restrict__ trw, const unsigned short* __restrict__ gpart,
          float* __restrict__ out, int P) {
    __shared__ float sh[32 * 16 * 8];   // 16 KB: [sub][oct][j]
    __shared__ float red2[8];

    const int tid = threadIdx.x;
    const int sub = tid >> 4;                  // 0..31 : b-split
    const int oct = tid & 15;
    const int tt  = blockIdx.x * 16 + oct;     // 0..4095 ; elements 8tt..8tt+7

    float g[8];
    #pragma unroll
    for (int j = 0; j < 8; ++j) g[j] = 0.f;

    const unsigned short* base = gpart + (size_t)tt * 8;
    for (int b = sub; b < P; b += 32) {
        half8 v = *(const half8*)(base + (size_t)b * GSZ);
        #pragma unroll
        for (int j = 0; j < 8; ++j) g[j] += (float)v[j];
    }
    #pragma unroll
    for (int j = 0; j < 8; ++j) sh[(sub * 16 + oct) * 8 + j] = g[j];
    __syncthreads();

    float val = 0.f;
    if (tid < 128) {
        const int o2 = tid >> 3, j = tid & 7;
        float s = 0.f;
        #pragma unroll
        for (int sb = 0; sb < 32; ++sb) s += sh[(sb * 16 + o2) * 8 + j];
        val = -s * s;
    } else if (blockIdx.x == 0) {
        for (int i = tid - 128; i < P; i += 384)   // covers all P trw partials
            val += trw[i];
    }

    #pragma unroll
    for (int off = 32; off > 0; off >>= 1) val += __shfl_down(val, off, 64);
    if ((tid & 63) == 0) red2[tid >> 6] = val;
    __syncthreads();
    if (tid == 0) {
        float s = 0.f;
        #pragma unroll
        for (int w = 0; w < 8; ++w) s += red2[w];
        atomicAdd(out, s);
    }
}

extern "C" void kernel_launch(void* const* d_in, const int* in_sizes, int n_in,
                              void* d_out, int out_size, void* d_ws, size_t ws_size,
                              hipStream_t stream) {
    const float* h = (const float*)d_in[0];   // [65536, 512]
    const float* F = (const float*)d_in[1];   // [65536, 64]
    float* out = (float*)d_out;

    // ws: [0,4096): trw fp32 (P<=512) ; [4096, 4096+P*64KiB): fp16 partial G
    int P = NBLK;
    while (P > 1 && (size_t)4096 + (size_t)P * (GSZ * 2) > ws_size) P >>= 1;
    const int rowsPerBlock = N_TOT / P;

    float* trw = (float*)d_ws;
    unsigned short* gpart = (unsigned short*)((char*)d_ws + 4096);

    hipLaunchKernelGGL(k1_partial, dim3(P), dim3(512), 0, stream,
                       h, F, trw, gpart, out, rowsPerBlock);
    hipLaunchKernelGGL(k2_reduce, dim3(256), dim3(512), 0, stream,
                       trw, gpart, out, P);
}

// Round 8
// 214.578 us; speedup vs baseline: 1.0084x; 1.0084x over previous
//
#include <hip/hip_runtime.h>
#include <hip/hip_fp16.h>
#include <hip/hip_bf16.h>

#define N_TOT 65536
#define D_DIM 512
#define K_DIM 64
#define SLABS 512               // n-slabs; rows per slab = 128
#define NC    32                // n-rows per MFMA K-step
#define GSZ   (K_DIM * D_DIM)   // 32768 elements of one slab's partial G

typedef __bf16   bf16x8 __attribute__((ext_vector_type(8)));
typedef float    f32x4  __attribute__((ext_vector_type(4)));
typedef _Float16 half8  __attribute__((ext_vector_type(8)));

union pk4 { unsigned int u[4]; bf16x8 v; };

__device__ __forceinline__ unsigned int pack2(float a, float b) {
    __hip_bfloat162 t = __float22bfloat162_rn(make_float2(a, b));
    union { __hip_bfloat162 h; unsigned int u; } r; r.h = t;
    return r.u;
}

// K1 v8: direct global->register MFMA, no LDS, no barriers, AMPLE VGPRs.
// R5's counter row (VGPR_Count=56 at 1024 thr) showed __launch_bounds__(1024)
// let the allocator squeeze the 48-wide load batch into ~4-wide load->wait
// chains -> 2.3 TB/s latency-bound. 256-thr blocks + __launch_bounds__(256,1)
// give a ~512-VGPR budget so the 64-wide batch survives: ~16 KB in flight per
// wave, ~3 waves/SIMD -> far above the ~22 KB/CU Little's-law requirement.
// Block = (n-slab, d-half); wave owns 64 d-cols; 4 chunks of NC=32 rows.
extern "C" __global__ void __launch_bounds__(256, 1)
k1_partial(const float* __restrict__ h, const float* __restrict__ F,
           float* __restrict__ trw_out, unsigned short* __restrict__ gpart,
           float* __restrict__ out) {
    __shared__ float red[4];

    const int tid   = threadIdx.x;
    const int bx    = blockIdx.x;
    const int slab  = bx >> 1;
    const int dhalf = bx & 1;
    if (bx == 0 && tid == 0) out[0] = 0.0f;   // d_out poisoned; zero before K2

    const int wave = tid >> 6;    // 0..3
    const int lane = tid & 63;
    const int m    = lane & 15;
    const int q    = lane >> 4;
    const int d0   = dhalf * 256 + wave * 64; // wave's 64 d-columns

    const int n0 = slab * 128;

    f32x4 acc[4][4];              // [kt][dt]
    #pragma unroll
    for (int kt = 0; kt < 4; ++kt)
        #pragma unroll
        for (int dt = 0; dt < 4; ++dt)
            acc[kt][dt] = (f32x4){0.f, 0.f, 0.f, 0.f};

    float trw = 0.f;

    for (int c = 0; c < 4; ++c) {             // 4 chunks of 32 n-rows
        const float* hb = h + (size_t)(n0 + c * NC + q * 8) * D_DIM + d0 + m;
        const float* fb = F + (size_t)(n0 + c * NC + q * 8) * K_DIM + m;

        // ---- all 64 loads issued before any use ----
        float vb[32], va[32];
        #pragma unroll
        for (int dt = 0; dt < 4; ++dt)
            #pragma unroll
            for (int j = 0; j < 8; ++j)
                vb[dt * 8 + j] = hb[(size_t)j * D_DIM + dt * 16];
        #pragma unroll
        for (int kt = 0; kt < 4; ++kt)
            #pragma unroll
            for (int j = 0; j < 8; ++j)
                va[kt * 8 + j] = fb[(size_t)j * K_DIM + kt * 16];

        // ---- pack + trw ----
        bf16x8 bfrag[4], afrag[4];
        #pragma unroll
        for (int dt = 0; dt < 4; ++dt) {
            pk4 pp;
            #pragma unroll
            for (int jj = 0; jj < 4; ++jj) {
                float a0 = vb[dt * 8 + 2 * jj], a1 = vb[dt * 8 + 2 * jj + 1];
                trw += a0 * a0 + a1 * a1;     // each h element once grid-wide
                pp.u[jj] = pack2(a0, a1);
            }
            bfrag[dt] = pp.v;
        }
        #pragma unroll
        for (int kt = 0; kt < 4; ++kt) {
            pk4 pp;
            #pragma unroll
            for (int jj = 0; jj < 4; ++jj)
                pp.u[jj] = pack2(va[kt * 8 + 2 * jj], va[kt * 8 + 2 * jj + 1]);
            afrag[kt] = pp.v;
        }

        // ---- 16 MFMAs ----
        #pragma unroll
        for (int kt = 0; kt < 4; ++kt)
            #pragma unroll
            for (int dt = 0; dt < 4; ++dt)
                acc[kt][dt] = __builtin_amdgcn_mfma_f32_16x16x32_bf16(
                    afrag[kt], bfrag[dt], acc[kt][dt], 0, 0, 0);
    }

    // ---- epilogue: slab partial G (this block's d-half) -> fp16 ----
    unsigned short* gp = gpart + (size_t)slab * GSZ;
    #pragma unroll
    for (int kt = 0; kt < 4; ++kt)
        #pragma unroll
        for (int dt = 0; dt < 4; ++dt)
            #pragma unroll
            for (int r = 0; r < 4; ++r) {
                const int k = kt * 16 + q * 4 + r;    // C/D row
                const int d = d0 + dt * 16 + m;       // C/D col
                __half hv = __float2half(acc[kt][dt][r]);
                gp[k * D_DIM + d] = *(unsigned short*)&hv;
            }

    // ---- trw partial per block ----
    #pragma unroll
    for (int off = 32; off > 0; off >>= 1) trw += __shfl_down(trw, off, 64);
    if (lane == 0) red[wave] = trw;
    __syncthreads();
    if (tid == 0)
        trw_out[bx] = red[0] + red[1] + red[2] + red[3];
}

// K2: out = sum_b trw[b] - sum_{k,d} (sum_s Gpart[s][k,d])^2   (256 blocks)
extern "C" __global__ void __launch_bounds__(512)
k2_reduce(const float* __restrict__ trw, const unsigned short* __restrict__ gpart,
          float* __restrict__ out, int Pg, int Pt) {
    __shared__ float sh[32 * 16 * 8];   // 16 KB: [sub][oct][j]
    __shared__ float red2[8];

    const int tid = threadIdx.x;
    const int sub = tid >> 4;                  // 0..31 : slab-split
    const int oct = tid & 15;
    const int tt  = blockIdx.x * 16 + oct;     // 0..4095 ; elements 8tt..8tt+7

    float g[8];
    #pragma unroll
    for (int j = 0; j < 8; ++j) g[j] = 0.f;

    const unsigned short* base = gpart + (size_t)tt * 8;
    for (int s = sub; s < Pg; s += 32) {
        half8 v = *(const half8*)(base + (size_t)s * GSZ);
        #pragma unroll
        for (int j = 0; j < 8; ++j) g[j] += (float)v[j];
    }
    #pragma unroll
    for (int j = 0; j < 8; ++j) sh[(sub * 16 + oct) * 8 + j] = g[j];
    __syncthreads();

    float val = 0.f;
    if (tid < 128) {
        const int o2 = tid >> 3, j = tid & 7;
        float s = 0.f;
        #pragma unroll
        for (int sb = 0; sb < 32; ++sb) s += sh[(sb * 16 + o2) * 8 + j];
        val = -s * s;
    } else if (blockIdx.x == 0) {
        for (int i = tid - 128; i < Pt; i += 384)  // all trw block-partials
            val += trw[i];
    }

    #pragma unroll
    for (int off = 32; off > 0; off >>= 1) val += __shfl_down(val, off, 64);
    if ((tid & 63) == 0) red2[tid >> 6] = val;
    __syncthreads();
    if (tid == 0) {
        float s = 0.f;
        #pragma unroll
        for (int w = 0; w < 8; ++w) s += red2[w];
        atomicAdd(out, s);
    }
}

extern "C" void kernel_launch(void* const* d_in, const int* in_sizes, int n_in,
                              void* d_out, int out_size, void* d_ws, size_t ws_size,
                              hipStream_t stream) {
    const float* h = (const float*)d_in[0];   // [65536, 512]
    const float* F = (const float*)d_in[1];   // [65536, 64]
    float* out = (float*)d_out;

    // ws: [0, 4096): trw fp32 (1024 block-partials);
    //     [4096, 4096 + SLABS*64KiB): fp16 slab partial G (32 MB)
    float* trw = (float*)d_ws;
    unsigned short* gpart = (unsigned short*)((char*)d_ws + 4096);

    hipLaunchKernelGGL(k1_partial, dim3(SLABS * 2), dim3(256), 0, stream,
                       h, F, trw, gpart, out);
    hipLaunchKernelGGL(k2_reduce, dim3(256), dim3(512), 0, stream,
                       trw, gpart, out, SLABS, SLABS * 2);
}